// Round 3
// baseline (122.977 us; speedup 1.0000x reference)
//
#include <hip/hip_runtime.h>

#define DK 256   // feature dim (K)
#define TT 1024  // T1 = T2
#define NB 16    // batch

typedef __attribute__((ext_vector_type(8))) short bf16x8;
typedef __attribute__((ext_vector_type(4))) float f32x4;

// HW packed fp32->bf16 (RNE). r[15:0]=bf16(lo), r[31:16]=bf16(hi).
__device__ __forceinline__ unsigned int cvt_pk_bf16(float lo, float hi) {
    unsigned int r;
    asm("v_cvt_pk_bf16_f32 %0, %1, %2" : "=v"(r) : "v"(lo), "v"(hi));
    return r;
}

union BF8 { uint4 u; bf16x8 v; };

// ---------------------------------------------------------------------------
// Fully fused: out[b,i,j] = sum_k bf16(x)[b,i,k]*bf16(w3*y)[b,j,k]
//                           + (x.w1)[b,i] + (y.w2)[b,j]
//
// R8 changes vs R7 (R7 post-mortem: nt stores REGRESSED (kernel 48us) ->
// reverted. First clean fused_kernel counters: hbm 26% of peak, MfmaUtil 6%,
// VALUBusy 10%, Occupancy 31.7% -> latency-bound. Root cause: acc[2][8]=64
// AGPR + 60 VGPR = 124/128 budget -> compiler cannot pipeline the global
// x-loads feeding MFMA; 64KB LDS caps residency at 2 blocks/CU (16 waves)):
//  * j-tile 128 -> 64: LDS 32.25KB -> 3 blocks/CU fit; acc[2][4]=32 AGPR
//    frees ~32 regs for load pipelining. __launch_bounds__(512,6) asks for
//    <=85 regs/thread (6 waves/SIMD = 24 waves/CU cap, was 16).
//  * grid 512 -> 1024 (b 16 x is 4 x jt 16); finer tail. Cost: x re-read
//    16x instead of 8x -- L2-served (~4us of L2 BW), acceptable.
//  * XCD decode unchanged (id%8 = b&7): per-XCD set = 2 batches x 2MB = 4MB L2.
//  * nt stores reverted to plain stores.
// ---------------------------------------------------------------------------
__global__ __launch_bounds__(512, 6) void fused_kernel(
    const float* __restrict__ x, const float* __restrict__ y,
    const float* __restrict__ WS, float* __restrict__ out)
{
    __shared__ unsigned short Bs[64 * DK];    // 32 KB
    __shared__ float tys[64];

    const int tid  = threadIdx.x;
    const int lane = tid & 63;
    const int w    = tid >> 6;                // wave 0..7

    // XCD-locality decode: id%8 = b&7 constant across is/jt groups
    const int id = blockIdx.x;                // 0..1023
    const int b  = id & 15;                   // batch
    const int is = (id >> 4) & 3;             // i slice (0..3), 256 rows
    const int jt = id >> 6;                   // j tile (0..15), 64 cols

    // ---- 1. stage B = bf16(w3*y) (XOR-swizzled), ty = y.w2
    {
        const float* gY0 = y + ((size_t)b * TT + jt * 64) * DK;
        const int c = tid & 31;               // 16B chunk within row (it-invariant)
        const float* w3p = WS + 2 * DK + c * 8;
        const float* w2p = WS + DK + c * 8;
        const float4 wa = *(const float4*)(w3p);
        const float4 wb = *(const float4*)(w3p + 4);
        const float4 va = *(const float4*)(w2p);
        const float4 vb = *(const float4*)(w2p + 4);
        #pragma unroll
        for (int it = 0; it < 4; ++it) {
            const int j = it * 16 + (tid >> 5);   // local row 0..63
            const float* gY = gY0 + (size_t)j * DK + c * 8;
            const float4 ya = *(const float4*)(gY);
            const float4 yb = *(const float4*)(gY + 4);
            float p = ya.x * va.x + ya.y * va.y + ya.z * va.z + ya.w * va.w
                    + yb.x * vb.x + yb.y * vb.y + yb.z * vb.z + yb.w * vb.w;
            uint4 o;
            o.x = cvt_pk_bf16(ya.x * wa.x, ya.y * wa.y);
            o.y = cvt_pk_bf16(ya.z * wa.z, ya.w * wa.w);
            o.z = cvt_pk_bf16(yb.x * wb.x, yb.y * wb.y);
            o.w = cvt_pk_bf16(yb.z * wb.z, yb.w * wb.w);
            const int slot = c ^ (j & 7);
            *(uint4*)(Bs + j * DK + slot * 8) = o;
            // reduce p across the 32 lanes sharing row j
            p += __shfl_xor(p, 1);
            p += __shfl_xor(p, 2);
            p += __shfl_xor(p, 4);
            p += __shfl_xor(p, 8);
            p += __shfl_xor(p, 16);
            if ((tid & 31) == 0) tys[j] = p;
        }
    }
    __syncthreads();                          // the ONLY barrier

    // ---- 2. barrier-free K-loop: wave owns 32 i-rows x 64 j-cols
    const int mfr  = lane & 15;
    const int quad = lane >> 4;
    const int i0   = is * 256 + w * 32;
    const float* gA = x + ((size_t)b * TT + i0) * DK;

    f32x4 acc[2][4];
    #pragma unroll
    for (int it = 0; it < 2; ++it)
        #pragma unroll
        for (int n = 0; n < 4; ++n)
            acc[it][n] = (f32x4){0.f, 0.f, 0.f, 0.f};
    float txp[2] = {0.f, 0.f};

    #pragma unroll
    for (int ks = 0; ks < 8; ++ks) {
        const float* w1p = WS + ks * 32 + quad * 8;
        const float4 w1a = *(const float4*)(w1p);
        const float4 w1b = *(const float4*)(w1p + 4);
        bf16x8 av[2];
        #pragma unroll
        for (int it = 0; it < 2; ++it) {
            const float* rp = gA + (size_t)(it * 16 + mfr) * DK
                              + ks * 32 + quad * 8;
            const float4 xa = *(const float4*)rp;
            const float4 xb = *(const float4*)(rp + 4);
            txp[it] += xa.x * w1a.x + xa.y * w1a.y + xa.z * w1a.z + xa.w * w1a.w
                     + xb.x * w1b.x + xb.y * w1b.y + xb.z * w1b.z + xb.w * w1b.w;
            BF8 cv;
            cv.u.x = cvt_pk_bf16(xa.x, xa.y);
            cv.u.y = cvt_pk_bf16(xa.z, xa.w);
            cv.u.z = cvt_pk_bf16(xb.x, xb.y);
            cv.u.w = cvt_pk_bf16(xb.z, xb.w);
            av[it] = cv.v;
        }
        #pragma unroll
        for (int n = 0; n < 4; ++n) {
            const int j    = n * 16 + mfr;
            const int slot = (ks * 4 + quad) ^ (j & 7);
            const bf16x8 bv = *(const bf16x8*)(Bs + j * DK + slot * 8);
            #pragma unroll
            for (int it = 0; it < 2; ++it)
                acc[it][n] = __builtin_amdgcn_mfma_f32_16x16x32_bf16(
                    av[it], bv, acc[it][n], 0, 0, 0);
        }
    }

    // ---- 3. epilogue: tx quad-reduction, + tx[i] + ty[j], fp32 stores
    #pragma unroll
    for (int it = 0; it < 2; ++it) {
        txp[it] += __shfl_xor(txp[it], 16);
        txp[it] += __shfl_xor(txp[it], 32);
        // lane now holds full tx for row i0 + it*16 + mfr
    }

    float tyv[4];
    #pragma unroll
    for (int n = 0; n < 4; ++n)
        tyv[n] = tys[n * 16 + mfr];

    float* outB = out + ((size_t)b << 20) + (size_t)i0 * TT + jt * 64;
    #pragma unroll
    for (int it = 0; it < 2; ++it) {
        #pragma unroll
        for (int r = 0; r < 4; ++r) {
            const int row = it * 16 + quad * 4 + r;
            // tx for this row lives at lanes with mfr == quad*4+r (any quad)
            const float trow = __shfl(txp[it], (lane & 48) | (quad * 4 + r));
            #pragma unroll
            for (int n = 0; n < 4; ++n)
                outB[(size_t)row * TT + n * 16 + mfr] =
                    acc[it][n][r] + trow + tyv[n];
        }
    }
}

extern "C" void kernel_launch(void* const* d_in, const int* in_sizes, int n_in,
                              void* d_out, int out_size, void* d_ws, size_t ws_size,
                              hipStream_t stream)
{
    const float* x  = (const float*)d_in[0];
    const float* y  = (const float*)d_in[1];
    const float* WS = (const float*)d_in[2];
    float* out = (float*)d_out;
    (void)d_ws; (void)ws_size;   // no workspace needed — fully fused

    fused_kernel<<<dim3(1024), dim3(512), 0, stream>>>(x, y, WS, out);
}

// Round 4
// 122.208 us; speedup vs baseline: 1.0063x; 1.0063x over previous
//
#include <hip/hip_runtime.h>

#define DK 256   // feature dim (K)
#define TT 1024  // T1 = T2
#define NB 16    // batch

typedef __attribute__((ext_vector_type(8))) short bf16x8;
typedef __attribute__((ext_vector_type(4))) float f32x4;

// HW packed fp32->bf16 (RNE). r[15:0]=bf16(lo), r[31:16]=bf16(hi).
__device__ __forceinline__ unsigned int cvt_pk_bf16(float lo, float hi) {
    unsigned int r;
    asm("v_cvt_pk_bf16_f32 %0, %1, %2" : "=v"(r) : "v"(lo), "v"(hi));
    return r;
}

union BF8 { uint4 u; bf16x8 v; };

// ---------------------------------------------------------------------------
// Fully fused: out[b,i,j] = sum_k bf16(x)[b,i,k]*bf16(w3*y)[b,j,k]
//                           + (x.w1)[b,i] + (y.w2)[b,j]
//
// R9 = R6 structure (best measured: kernel ~42us, jt=128, 512 blocks,
// launch_bounds(512,4)) + ONE change, from the R8 post-mortem diagnosis
// (latency-bound: MfmaUtil 5.6%, VALU 12%, hbm 21%, occupancy unmoved by
// smaller tiles -> the serial chain is x global-load -> cvt -> MFMA with
// ~2 loads in flight):
//  * T14 async-split for x: distance-1 register double-buffer. ks=0 loads
//    issue BEFORE the y-stage phase (latency hides under staging+barrier);
//    ks+1 loads issue before ks's MFMA cluster (~180cy MFMA/ds cover).
//    Buffers indexed by ks&1 under full unroll (compile-time, no scratch).
//  * R8's jt=64 reverted (halved MFMA-per-load density; regressed to 55us).
//  * nt stores stay reverted (R7: -6us regression).
// ---------------------------------------------------------------------------
__global__ __launch_bounds__(512, 4) void fused_kernel(
    const float* __restrict__ x, const float* __restrict__ y,
    const float* __restrict__ WS, float* __restrict__ out)
{
    __shared__ unsigned short Bs[128 * DK];   // 64 KB
    __shared__ float tys[128];

    const int tid  = threadIdx.x;
    const int lane = tid & 63;
    const int w    = tid >> 6;                // wave 0..7

    // XCD-locality decode: id%8 constant across the jt group and the is group
    const int id = blockIdx.x;                // 0..511
    const int b  = id & 15;                   // batch
    const int is = (id >> 4) & 3;             // i slice (0..3), 256 rows
    const int jt = id >> 6;                   // j tile (0..7), 128 cols

    // wave-constant geometry needed for the x prefetch (issued pre-stage)
    const int mfr  = lane & 15;
    const int quad = lane >> 4;
    const int i0   = is * 256 + w * 32;
    const float* gA = x + ((size_t)b * TT + i0) * DK;

    // ---- 0. T14: issue ks=0 x-loads; latency hides under the whole y-stage
    float4 xp[2][2][2];                       // [parity][it][lo/hi]
    #pragma unroll
    for (int it = 0; it < 2; ++it) {
        const float* rp = gA + (size_t)(it * 16 + mfr) * DK + quad * 8;
        xp[0][it][0] = *(const float4*)rp;
        xp[0][it][1] = *(const float4*)(rp + 4);
    }

    // ---- 1. stage B = bf16(w3*y) (XOR-swizzled), ty = y.w2
    {
        const float* gY0 = y + ((size_t)b * TT + jt * 128) * DK;
        const int c = tid & 31;               // 16B chunk within row (it-invariant)
        const float* w3p = WS + 2 * DK + c * 8;
        const float* w2p = WS + DK + c * 8;
        const float4 wa = *(const float4*)(w3p);
        const float4 wb = *(const float4*)(w3p + 4);
        const float4 va = *(const float4*)(w2p);
        const float4 vb = *(const float4*)(w2p + 4);
        #pragma unroll
        for (int it = 0; it < 8; ++it) {
            const int j = it * 16 + (tid >> 5);   // local row 0..127
            const float* gY = gY0 + (size_t)j * DK + c * 8;
            const float4 ya = *(const float4*)(gY);
            const float4 yb = *(const float4*)(gY + 4);
            float p = ya.x * va.x + ya.y * va.y + ya.z * va.z + ya.w * va.w
                    + yb.x * vb.x + yb.y * vb.y + yb.z * vb.z + yb.w * vb.w;
            uint4 o;
            o.x = cvt_pk_bf16(ya.x * wa.x, ya.y * wa.y);
            o.y = cvt_pk_bf16(ya.z * wa.z, ya.w * wa.w);
            o.z = cvt_pk_bf16(yb.x * wb.x, yb.y * wb.y);
            o.w = cvt_pk_bf16(yb.z * wb.z, yb.w * wb.w);
            const int slot = c ^ (j & 7);
            *(uint4*)(Bs + j * DK + slot * 8) = o;
            // reduce p across the 32 lanes sharing row j
            p += __shfl_xor(p, 1);
            p += __shfl_xor(p, 2);
            p += __shfl_xor(p, 4);
            p += __shfl_xor(p, 8);
            p += __shfl_xor(p, 16);
            if ((tid & 31) == 0) tys[j] = p;
        }
    }
    __syncthreads();                          // the ONLY barrier

    // ---- 2. K-loop with distance-1 x prefetch: wave owns 32 i-rows
    f32x4 acc[2][8];
    #pragma unroll
    for (int it = 0; it < 2; ++it)
        #pragma unroll
        for (int n = 0; n < 8; ++n)
            acc[it][n] = (f32x4){0.f, 0.f, 0.f, 0.f};
    float txp[2] = {0.f, 0.f};

    #pragma unroll
    for (int ks = 0; ks < 8; ++ks) {
        const int cur = ks & 1;
        const int nxt = cur ^ 1;
        // issue next-step loads BEFORE this step's compute (dist-1 pipeline)
        if (ks < 7) {
            #pragma unroll
            for (int it = 0; it < 2; ++it) {
                const float* rp = gA + (size_t)(it * 16 + mfr) * DK
                                  + (ks + 1) * 32 + quad * 8;
                xp[nxt][it][0] = *(const float4*)rp;
                xp[nxt][it][1] = *(const float4*)(rp + 4);
            }
        }
        const float* w1p = WS + ks * 32 + quad * 8;
        const float4 w1a = *(const float4*)(w1p);
        const float4 w1b = *(const float4*)(w1p + 4);
        bf16x8 av[2];
        #pragma unroll
        for (int it = 0; it < 2; ++it) {
            const float4 xa = xp[cur][it][0];
            const float4 xb = xp[cur][it][1];
            txp[it] += xa.x * w1a.x + xa.y * w1a.y + xa.z * w1a.z + xa.w * w1a.w
                     + xb.x * w1b.x + xb.y * w1b.y + xb.z * w1b.z + xb.w * w1b.w;
            BF8 cv;
            cv.u.x = cvt_pk_bf16(xa.x, xa.y);
            cv.u.y = cvt_pk_bf16(xa.z, xa.w);
            cv.u.z = cvt_pk_bf16(xb.x, xb.y);
            cv.u.w = cvt_pk_bf16(xb.z, xb.w);
            av[it] = cv.v;
        }
        #pragma unroll
        for (int n = 0; n < 8; ++n) {
            const int j    = n * 16 + mfr;
            const int slot = (ks * 4 + quad) ^ (j & 7);
            const bf16x8 bv = *(const bf16x8*)(Bs + j * DK + slot * 8);
            #pragma unroll
            for (int it = 0; it < 2; ++it)
                acc[it][n] = __builtin_amdgcn_mfma_f32_16x16x32_bf16(
                    av[it], bv, acc[it][n], 0, 0, 0);
        }
    }

    // ---- 3. epilogue: tx quad-reduction, + tx[i] + ty[j], fp32 stores
    #pragma unroll
    for (int it = 0; it < 2; ++it) {
        txp[it] += __shfl_xor(txp[it], 16);
        txp[it] += __shfl_xor(txp[it], 32);
        // lane now holds full tx for row i0 + it*16 + mfr
    }

    float tyv[8];
    #pragma unroll
    for (int n = 0; n < 8; ++n)
        tyv[n] = tys[n * 16 + mfr];

    float* outB = out + ((size_t)b << 20) + (size_t)i0 * TT + jt * 128;
    #pragma unroll
    for (int it = 0; it < 2; ++it) {
        #pragma unroll
        for (int r = 0; r < 4; ++r) {
            const int row = it * 16 + quad * 4 + r;
            // tx for this row lives at lanes with mfr == quad*4+r (any quad)
            const float trow = __shfl(txp[it], (lane & 48) | (quad * 4 + r));
            #pragma unroll
            for (int n = 0; n < 8; ++n)
                outB[(size_t)row * TT + n * 16 + mfr] =
                    acc[it][n][r] + trow + tyv[n];
        }
    }
}

extern "C" void kernel_launch(void* const* d_in, const int* in_sizes, int n_in,
                              void* d_out, int out_size, void* d_ws, size_t ws_size,
                              hipStream_t stream)
{
    const float* x  = (const float*)d_in[0];
    const float* y  = (const float*)d_in[1];
    const float* WS = (const float*)d_in[2];
    float* out = (float*)d_out;
    (void)d_ws; (void)ws_size;   // no workspace needed — fully fused

    fused_kernel<<<dim3(512), dim3(512), 0, stream>>>(x, y, WS, out);
}

// Round 5
// 121.345 us; speedup vs baseline: 1.0134x; 1.0071x over previous
//
#include <hip/hip_runtime.h>

#define DK 256   // feature dim (K)
#define TT 1024  // T1 = T2
#define NB 16    // batch

typedef __attribute__((ext_vector_type(8))) short bf16x8;
typedef __attribute__((ext_vector_type(4))) float f32x4;

// HW packed fp32->bf16 (RNE). r[15:0]=bf16(lo), r[31:16]=bf16(hi).
__device__ __forceinline__ unsigned int cvt_pk_bf16(float lo, float hi) {
    unsigned int r;
    asm("v_cvt_pk_bf16_f32 %0, %1, %2" : "=v"(r) : "v"(lo), "v"(hi));
    return r;
}

union BF8 { uint4 u; bf16x8 v; };

// ---------------------------------------------------------------------------
// Fully fused: out[b,i,j] = sum_k bf16(x)[b,i,k]*bf16(w3*y)[b,j,k]
//                           + (x.w1)[b,i] + (y.w2)[b,j]
//
// R10 = R9 with ONE change: __launch_bounds__(512,4) -> (512,3).
// R9 post-mortem: WRITE_SIZE 107MB (vs 67MB output) + FETCH 30.6MB (vs 16.5)
// = ~54MB of scratch-spill traffic. acc[2][8]=64 AGPR + 64 VGPR hit the
// 128-reg cap of (512,4); the xp[2][2][2] prefetch buffers (32 regs) were
// spilled, so the dist-1 prefetch never actually ran from registers.
// (512,3) caps at ~170 regs (pool 512/SIMD): 64 acc + 32 prefetch + ~60
// working = ~156, fits. Occupancy cost nil: measured residency was ~10
// waves/CU (<12 cap); LDS already limited us to 16.
//  * Confirmation signal: WRITE back to ~67MB, FETCH ~16.5MB.
//  * If kernel returns only to ~36us (prefetch neutral): register-level
//    pipelining exhausted -> next step is global_load_lds DMA panels.
// ---------------------------------------------------------------------------
__global__ __launch_bounds__(512, 3) void fused_kernel(
    const float* __restrict__ x, const float* __restrict__ y,
    const float* __restrict__ WS, float* __restrict__ out)
{
    __shared__ unsigned short Bs[128 * DK];   // 64 KB
    __shared__ float tys[128];

    const int tid  = threadIdx.x;
    const int lane = tid & 63;
    const int w    = tid >> 6;                // wave 0..7

    // XCD-locality decode: id%8 constant across the jt group and the is group
    const int id = blockIdx.x;                // 0..511
    const int b  = id & 15;                   // batch
    const int is = (id >> 4) & 3;             // i slice (0..3), 256 rows
    const int jt = id >> 6;                   // j tile (0..7), 128 cols

    // wave-constant geometry needed for the x prefetch (issued pre-stage)
    const int mfr  = lane & 15;
    const int quad = lane >> 4;
    const int i0   = is * 256 + w * 32;
    const float* gA = x + ((size_t)b * TT + i0) * DK;

    // ---- 0. T14: issue ks=0 x-loads; latency hides under the whole y-stage
    float4 xp[2][2][2];                       // [parity][it][lo/hi]
    #pragma unroll
    for (int it = 0; it < 2; ++it) {
        const float* rp = gA + (size_t)(it * 16 + mfr) * DK + quad * 8;
        xp[0][it][0] = *(const float4*)rp;
        xp[0][it][1] = *(const float4*)(rp + 4);
    }

    // ---- 1. stage B = bf16(w3*y) (XOR-swizzled), ty = y.w2
    {
        const float* gY0 = y + ((size_t)b * TT + jt * 128) * DK;
        const int c = tid & 31;               // 16B chunk within row (it-invariant)
        const float* w3p = WS + 2 * DK + c * 8;
        const float* w2p = WS + DK + c * 8;
        const float4 wa = *(const float4*)(w3p);
        const float4 wb = *(const float4*)(w3p + 4);
        const float4 va = *(const float4*)(w2p);
        const float4 vb = *(const float4*)(w2p + 4);
        #pragma unroll
        for (int it = 0; it < 8; ++it) {
            const int j = it * 16 + (tid >> 5);   // local row 0..127
            const float* gY = gY0 + (size_t)j * DK + c * 8;
            const float4 ya = *(const float4*)(gY);
            const float4 yb = *(const float4*)(gY + 4);
            float p = ya.x * va.x + ya.y * va.y + ya.z * va.z + ya.w * va.w
                    + yb.x * vb.x + yb.y * vb.y + yb.z * vb.z + yb.w * vb.w;
            uint4 o;
            o.x = cvt_pk_bf16(ya.x * wa.x, ya.y * wa.y);
            o.y = cvt_pk_bf16(ya.z * wa.z, ya.w * wa.w);
            o.z = cvt_pk_bf16(yb.x * wb.x, yb.y * wb.y);
            o.w = cvt_pk_bf16(yb.z * wb.z, yb.w * wb.w);
            const int slot = c ^ (j & 7);
            *(uint4*)(Bs + j * DK + slot * 8) = o;
            // reduce p across the 32 lanes sharing row j
            p += __shfl_xor(p, 1);
            p += __shfl_xor(p, 2);
            p += __shfl_xor(p, 4);
            p += __shfl_xor(p, 8);
            p += __shfl_xor(p, 16);
            if ((tid & 31) == 0) tys[j] = p;
        }
    }
    __syncthreads();                          // the ONLY barrier

    // ---- 2. K-loop with distance-1 x prefetch: wave owns 32 i-rows
    f32x4 acc[2][8];
    #pragma unroll
    for (int it = 0; it < 2; ++it)
        #pragma unroll
        for (int n = 0; n < 8; ++n)
            acc[it][n] = (f32x4){0.f, 0.f, 0.f, 0.f};
    float txp[2] = {0.f, 0.f};

    #pragma unroll
    for (int ks = 0; ks < 8; ++ks) {
        const int cur = ks & 1;
        const int nxt = cur ^ 1;
        // issue next-step loads BEFORE this step's compute (dist-1 pipeline)
        if (ks < 7) {
            #pragma unroll
            for (int it = 0; it < 2; ++it) {
                const float* rp = gA + (size_t)(it * 16 + mfr) * DK
                                  + (ks + 1) * 32 + quad * 8;
                xp[nxt][it][0] = *(const float4*)rp;
                xp[nxt][it][1] = *(const float4*)(rp + 4);
            }
        }
        const float* w1p = WS + ks * 32 + quad * 8;
        const float4 w1a = *(const float4*)(w1p);
        const float4 w1b = *(const float4*)(w1p + 4);
        bf16x8 av[2];
        #pragma unroll
        for (int it = 0; it < 2; ++it) {
            const float4 xa = xp[cur][it][0];
            const float4 xb = xp[cur][it][1];
            txp[it] += xa.x * w1a.x + xa.y * w1a.y + xa.z * w1a.z + xa.w * w1a.w
                     + xb.x * w1b.x + xb.y * w1b.y + xb.z * w1b.z + xb.w * w1b.w;
            BF8 cv;
            cv.u.x = cvt_pk_bf16(xa.x, xa.y);
            cv.u.y = cvt_pk_bf16(xa.z, xa.w);
            cv.u.z = cvt_pk_bf16(xb.x, xb.y);
            cv.u.w = cvt_pk_bf16(xb.z, xb.w);
            av[it] = cv.v;
        }
        #pragma unroll
        for (int n = 0; n < 8; ++n) {
            const int j    = n * 16 + mfr;
            const int slot = (ks * 4 + quad) ^ (j & 7);
            const bf16x8 bv = *(const bf16x8*)(Bs + j * DK + slot * 8);
            #pragma unroll
            for (int it = 0; it < 2; ++it)
                acc[it][n] = __builtin_amdgcn_mfma_f32_16x16x32_bf16(
                    av[it], bv, acc[it][n], 0, 0, 0);
        }
    }

    // ---- 3. epilogue: tx quad-reduction, + tx[i] + ty[j], fp32 stores
    #pragma unroll
    for (int it = 0; it < 2; ++it) {
        txp[it] += __shfl_xor(txp[it], 16);
        txp[it] += __shfl_xor(txp[it], 32);
        // lane now holds full tx for row i0 + it*16 + mfr
    }

    float tyv[8];
    #pragma unroll
    for (int n = 0; n < 8; ++n)
        tyv[n] = tys[n * 16 + mfr];

    float* outB = out + ((size_t)b << 20) + (size_t)i0 * TT + jt * 128;
    #pragma unroll
    for (int it = 0; it < 2; ++it) {
        #pragma unroll
        for (int r = 0; r < 4; ++r) {
            const int row = it * 16 + quad * 4 + r;
            // tx for this row lives at lanes with mfr == quad*4+r (any quad)
            const float trow = __shfl(txp[it], (lane & 48) | (quad * 4 + r));
            #pragma unroll
            for (int n = 0; n < 8; ++n)
                outB[(size_t)row * TT + n * 16 + mfr] =
                    acc[it][n][r] + trow + tyv[n];
        }
    }
}

extern "C" void kernel_launch(void* const* d_in, const int* in_sizes, int n_in,
                              void* d_out, int out_size, void* d_ws, size_t ws_size,
                              hipStream_t stream)
{
    const float* x  = (const float*)d_in[0];
    const float* y  = (const float*)d_in[1];
    const float* WS = (const float*)d_in[2];
    float* out = (float*)d_out;
    (void)d_ws; (void)ws_size;   // no workspace needed — fully fused

    fused_kernel<<<dim3(512), dim3(512), 0, stream>>>(x, y, WS, out);
}